// Round 12
// baseline (874.097 us; speedup 1.0000x reference)
//
#include <hip/hip_runtime.h>
#include <hip/hip_bf16.h>

#define K_DIM 4096
#define N_DIM 4096
#define R_DIM 16
#define SCALING_F 2.0f

#define BM 256
#define BN 256
#define BK 64   // bf16 elems per K-tile; 128 bytes per LDS row

#define FOLD_ROWS 8
#define FOLD_BLOCKS (N_DIM / FOLD_ROWS)   // 512

typedef __attribute__((ext_vector_type(8))) short bf16x8;
typedef __attribute__((ext_vector_type(4))) float f32x4;

__device__ __forceinline__ ushort f2bf(float f) {
  union { float f; unsigned u; } v; v.f = f;
  unsigned u = v.u;
  u += 0x7FFF + ((u >> 16) & 1);   // round-to-nearest-even
  return (ushort)(u >> 16);
}

// ---- fused pre-pass (r8, measured at its ~288MB HBM floor) ----
__global__ __launch_bounds__(256) void prepass_kernel(
    const float* __restrict__ x, ushort* __restrict__ xb,
    const float* __restrict__ W, const float* __restrict__ A,
    const float* __restrict__ Bl, ushort* __restrict__ wb, long n4) {
  if (blockIdx.x < FOLD_BLOCKS) {
    const int o0 = blockIdx.x * FOLD_ROWS;
#pragma unroll 1
    for (int j = 0; j < 4; ++j) {
      const int d0 = (threadIdx.x + j * 256) * 4;
      float4 a[R_DIM];
#pragma unroll
      for (int r = 0; r < R_DIM; ++r)
        a[r] = *(const float4*)(A + (size_t)r * K_DIM + d0);
#pragma unroll 1
      for (int rr = 0; rr < FOLD_ROWS; ++rr) {
        const int o = o0 + rr;
        float4 w = *(const float4*)(W + (size_t)o * K_DIM + d0);
        float s0 = w.x, s1 = w.y, s2 = w.z, s3 = w.w;
#pragma unroll
        for (int r = 0; r < R_DIM; ++r) {
          const float bv = Bl[o * R_DIM + r] * SCALING_F;  // uniform -> sgpr
          s0 += bv * a[r].x; s1 += bv * a[r].y;
          s2 += bv * a[r].z; s3 += bv * a[r].w;
        }
        ushort4 ob;
        ob.x = f2bf(s0); ob.y = f2bf(s1); ob.z = f2bf(s2); ob.w = f2bf(s3);
        *(ushort4*)(wb + (size_t)o * K_DIM + d0) = ob;
      }
    }
  } else {
    long i = (long)(blockIdx.x - FOLD_BLOCKS) * blockDim.x + threadIdx.x;
    long stride = 2048L * blockDim.x;
    for (; i < n4; i += stride) {
      long idx = i * 4;
      float4 v = *(const float4*)(x + idx);
      ushort4 o;
      o.x = f2bf(v.x); o.y = f2bf(v.y); o.z = f2bf(v.z); o.w = f2bf(v.w);
      *(ushort4*)(xb + idx) = o;
    }
  }
}

// ============================ 256x256 8-phase GEMM ============================
// r6 ledger skeleton + REGISTER-NEUTRAL fragment ping-pong:
//  - phase order per K-tile: (m4-7,k0),(m0-3,k0),(m4-7,k1),(m0-3,k1)
//    -> bfr single-kh (bfr[4], 16 regs) reloaded nn-major inside clusters
//  - afrA/afrB ping-pong (16+16): each phase pre-issues the OTHER set's 4
//    A-reads before its open-barrier (no WAR) -> they drain during MFMA
//  - lgkmcnt(4) at phase open retires everything except the 4 new A-reads
//  - stages: Ae(t1,b1)@ph1 | Ao,B0(t2,b0)@ph4 | Ae,B1(t2,b0)@ph5 |
//            Ao,B0,B1(t3,b1)@ph8  (each >=1 barrier after its region's
//            reads were lgkm-retired — ledger-verified)
//  - publish: vmcnt(0)+barrier at ph3-close (b1 tile) and ph7-close (b0
//    tile); newest stage has >=2 phases of flight (>= HBM latency)
// Frag regs 48 = r6 exactly -> fits the 256/wave unified cap (acc 128).

#define RS 8192L  // global row stride bytes (K_DIM * 2)

#define GLOAD(SRC, LOFF)                                                    \
  __builtin_amdgcn_global_load_lds(                                         \
      (const __attribute__((address_space(1))) void*)(SRC),                 \
      (__attribute__((address_space(3))) void*)(smem + (LOFF)), 16, 0, 0)

#define LDSA(BUF) ((BUF) * 32768)
#define LDSB(BUF) (65536 + (BUF) * 32768)

#define ST_A_EVEN(T, BUF) do {                                              \
    GLOAD(aS + (size_t)(T) * 128,            LDSA(BUF) + ldsDst);           \
    GLOAD(aS + (size_t)(T) * 128 + 128 * RS, LDSA(BUF) + 16384 + ldsDst); } while (0)
#define ST_A_ODD(T, BUF) do {                                               \
    GLOAD(aS + (size_t)(T) * 128 + 64 * RS,  LDSA(BUF) + 8192 + ldsDst);    \
    GLOAD(aS + (size_t)(T) * 128 + 192 * RS, LDSA(BUF) + 24576 + ldsDst); } while (0)
#define ST_B_H0(T, BUF) do {                                                \
    GLOAD(bS + (size_t)(T) * 128,            LDSB(BUF) + ldsDst);           \
    GLOAD(bS + (size_t)(T) * 128 + 64 * RS,  LDSB(BUF) + 8192 + ldsDst); } while (0)
#define ST_B_H1(T, BUF) do {                                                \
    GLOAD(bS + (size_t)(T) * 128 + 128 * RS, LDSB(BUF) + 16384 + ldsDst);   \
    GLOAD(bS + (size_t)(T) * 128 + 192 * RS, LDSB(BUF) + 24576 + ldsDst); } while (0)

#define LDA(M, CK, BUF) (*(const bf16x8*)(smem + LDSA(BUF) + aRd + (M) * 2048 + (CK)))
#define LDB(N, CK, BUF) (*(const bf16x8*)(smem + LDSB(BUF) + bRd + (N) * 2048 + (CK)))

// ping-pong A-read: fill SET with m-frags MB..MB+3 at column CK of BUF
#define RD_A(SET, MB, CK, BUF) do {                                         \
    SET[0] = LDA((MB) + 0, CK, BUF); SET[1] = LDA((MB) + 1, CK, BUF);       \
    SET[2] = LDA((MB) + 2, CK, BUF); SET[3] = LDA((MB) + 3, CK, BUF); } while (0)

// plain cluster: acc[MB..MB+3][*] += SET x bfr
#define CL16(SET, MB) do {                                                  \
    _Pragma("unroll") for (int nn = 0; nn < 4; ++nn)                        \
      _Pragma("unroll") for (int mm = 0; mm < 4; ++mm)                      \
        acc[(MB) + mm][nn] = __builtin_amdgcn_mfma_f32_16x16x32_bf16(       \
            SET[mm], bfr[nn], acc[(MB) + mm][nn], 0, 0, 0); } while (0)

// cluster with B reload: after bfr[nn]'s 4 uses, refill it (same-reg WAR)
#define CL16_BR(SET, MB, NCK, NBUF) do {                                    \
    _Pragma("unroll") for (int nn = 0; nn < 4; ++nn) {                      \
      _Pragma("unroll") for (int mm = 0; mm < 4; ++mm)                      \
        acc[(MB) + mm][nn] = __builtin_amdgcn_mfma_f32_16x16x32_bf16(       \
            SET[mm], bfr[nn], acc[(MB) + mm][nn], 0, 0, 0);                 \
      bfr[nn] = LDB(nn, NCK, NBUF);                                         \
    } } while (0)

#define PH_OPEN(N) do {                                                     \
    __builtin_amdgcn_s_barrier();                                           \
    asm volatile("s_waitcnt lgkmcnt(" #N ")");                              \
    __builtin_amdgcn_s_setprio(1); } while (0)

#define PH_CLOSE() do {                                                     \
    __builtin_amdgcn_s_setprio(0);                                          \
    __builtin_amdgcn_s_barrier(); } while (0)

#define PH_CLOSE_PUB() do {                                                 \
    __builtin_amdgcn_s_setprio(0);                                          \
    asm volatile("s_waitcnt vmcnt(0)" ::: "memory");                        \
    __builtin_amdgcn_s_barrier(); } while (0)

__global__ __launch_bounds__(512, 2) void gemm_lora_kernel(
    const ushort* __restrict__ Ab, const ushort* __restrict__ Bb,
    const float* __restrict__ bias, float* __restrict__ C) {
  __shared__ char smem[131072];

  const int tid = threadIdx.x;
  const int wave = tid >> 6, lane = tid & 63;
  const int wm = wave >> 2, wn = wave & 3;
  const int fr = lane & 15, fq = lane >> 4;

  // XCD-aware mapping: XCD x owns bm in [4x,4x+4); bn sweeps. grid=512 (%8==0).
  const int bid = blockIdx.x;
  const int bm = ((bid & 7) << 2) + ((bid >> 3) & 3);
  const int bn = bid >> 5;

  // staging source (inverse-swizzled global addresses, 16B chunks)
  const int trow = tid >> 3;
  const int tswz = ((tid & 7) << 4) ^ ((trow & 7) << 4);
  const char* aS = (const char*)Ab + (size_t)(bm * BM + trow) * RS + tswz;
  const char* bS = (const char*)Bb + (size_t)(bn * BN + trow) * RS + tswz;
  const int ldsDst = tid << 4;

  // swizzled ds_read byte columns (verified 0-conflict r2/r5/r6/r11)
  const int sa  = (fr & 7) << 4;
  const int cK0 = (fq << 4) ^ sa;
  const int cK1 = (64 | (fq << 4)) ^ sa;
  const int aRd = ((wm << 7) + fr) << 7;   // (wm*128 + fr) * 128 B
  const int bRd = ((wn << 6) + fr) << 7;   // (wn*64  + fr) * 128 B

  f32x4 acc[8][4];
#pragma unroll
  for (int m = 0; m < 8; ++m)
#pragma unroll
    for (int n = 0; n < 4; ++n) acc[m][n] = (f32x4){0.f, 0.f, 0.f, 0.f};
  bf16x8 afrA[4], afrB[4], bfr[4];

  // prologue: t0 -> b0 full (8 gloads); t1 -> b1: Ao,B0,B1 (6 gloads).
  ST_B_H0(0, 0); ST_B_H1(0, 0); ST_A_EVEN(0, 0); ST_A_ODD(0, 0);
  ST_A_ODD(1, 1); ST_B_H0(1, 1); ST_B_H1(1, 1);
  asm volatile("s_waitcnt vmcnt(6)" ::: "memory");  // t0 fully landed
  __builtin_amdgcn_s_barrier();                      // ...and visible to all
  // initial reads for ph1: afrB=(m4-7,k0,b0), bfr=B(k0,b0)
#pragma unroll
  for (int n = 0; n < 4; ++n) bfr[n] = LDB(n, cK0, 0);
  RD_A(afrB, 4, cK0, 0);

  const int NIT = K_DIM / (2 * BK);  // 32
#pragma unroll 1
  for (int i = 0; i < NIT; ++i) {
    const int t1 = 2 * i + 1, t2 = 2 * i + 2, t3 = 2 * i + 3;
    const bool last = (i == NIT - 1);

    // ---- ph1: b0 (m4-7,k0) on afrB | pre: afrA<-(m0-3,k0,b0), Ae(t1,b1) ----
    RD_A(afrA, 0, cK0, 0);
    ST_A_EVEN(t1, 1);
    PH_OPEN(4);
    CL16(afrB, 4);
    PH_CLOSE();

    // ---- ph2: b0 (m0-3,k0) on afrA, reload bfr<-B(k1,b0) | pre: afrB ----
    RD_A(afrB, 4, cK1, 0);
    PH_OPEN(4);
    CL16_BR(afrA, 0, cK1, 0);
    PH_CLOSE();

    // ---- ph3: b0 (m4-7,k1) on afrB | pre: afrA<-(m0-3,k1,b0) ----
    RD_A(afrA, 0, cK1, 0);
    PH_OPEN(4);
    CL16(afrB, 4);
    PH_CLOSE_PUB();                        // publishes b1 (t1): Ao,B0,B1@ph8' + Ae@ph1

    // ---- ph4: b0 (m0-3,k1) on afrA, reload bfr<-B(k0,b1) | pre: afrB<-b1 ----
    RD_A(afrB, 4, cK0, 1);
    if (!last) { ST_A_ODD(t2, 0); ST_B_H0(t2, 0); }
    PH_OPEN(4);
    CL16_BR(afrA, 0, cK0, 1);
    PH_CLOSE();

    // ---- ph5: b1 (m4-7,k0) on afrB | pre: afrA<-(m0-3,k0,b1) ----
    RD_A(afrA, 0, cK0, 1);
    if (!last) { ST_A_EVEN(t2, 0); ST_B_H1(t2, 0); }
    PH_OPEN(4);
    CL16(afrB, 4);
    PH_CLOSE();

    // ---- ph6: b1 (m0-3,k0) on afrA, reload bfr<-B(k1,b1) | pre: afrB ----
    RD_A(afrB, 4, cK1, 1);
    PH_OPEN(4);
    CL16_BR(afrA, 0, cK1, 1);
    PH_CLOSE();

    // ---- ph7: b1 (m4-7,k1) on afrB | pre: afrA<-(m0-3,k1,b1) ----
    RD_A(afrA, 0, cK1, 1);
    PH_OPEN(4);
    CL16(afrB, 4);
    PH_CLOSE_PUB();                        // publishes b0 (t2): Ao,B0@ph4 + Ae,B1@ph5

    // ---- ph8: b1 (m0-3,k1) on afrA, reload bfr<-B(k0,b0-t2) | pre: afrB ----
    if (!last) {
      RD_A(afrB, 4, cK0, 0);
      ST_A_ODD(t3, 1); ST_B_H0(t3, 1); ST_B_H1(t3, 1);
      PH_OPEN(4);
      CL16_BR(afrA, 0, cK0, 0);
      PH_CLOSE();
    } else {
      PH_OPEN(0);
      CL16(afrA, 0);
      __builtin_amdgcn_s_setprio(0);
    }
  }

  // epilogue: C/D layout col=lane&15, row=(lane>>4)*4+reg  [m89/m91]
  const int ccol0 = bn * BN + wn * 64 + fr;
  float bv[4];
#pragma unroll
  for (int n = 0; n < 4; ++n) bv[n] = bias[ccol0 + n * 16];
  const int crow0 = bm * BM + wm * 128 + fq * 4;
#pragma unroll
  for (int m = 0; m < 8; ++m)
#pragma unroll
    for (int n = 0; n < 4; ++n)
#pragma unroll
      for (int v = 0; v < 4; ++v) {
        int row = crow0 + m * 16 + v;
        C[(size_t)row * N_DIM + ccol0 + n * 16] = acc[m][n][v] + bv[n];
      }
}

extern "C" void kernel_launch(void* const* d_in, const int* in_sizes, int n_in,
                              void* d_out, int out_size, void* d_ws, size_t ws_size,
                              hipStream_t stream) {
  const float* x  = (const float*)d_in[0];   // [M, K]
  const float* W  = (const float*)d_in[1];   // [N, K]
  const float* b  = (const float*)d_in[2];   // [N]
  const float* lA = (const float*)d_in[3];   // [R, K]
  const float* lB = (const float*)d_in[4];   // [N, R]
  float* out = (float*)d_out;                // [M, N]

  const int M = in_sizes[0] / K_DIM;  // 8192

  ushort* xb = (ushort*)d_ws;                 // 64 MB
  ushort* wb = xb + (size_t)M * K_DIM;        // 32 MB

  long n4 = (long)M * K_DIM / 4;
  prepass_kernel<<<FOLD_BLOCKS + 2048, 256, 0, stream>>>(x, xb, W, lA, lB, wb, n4);
  gemm_lora_kernel<<<(M / BM) * (N_DIM / BN), 512, 0, stream>>>(xb, wb, b, out);
}

// Round 13
// 285.797 us; speedup vs baseline: 3.0585x; 3.0585x over previous
//
#include <hip/hip_runtime.h>
#include <hip/hip_bf16.h>

#define K_DIM 4096
#define N_DIM 4096
#define R_DIM 16
#define SCALING_F 2.0f

#define BM 256
#define BN 256
#define BK 64   // bf16 elems per K-tile; 128 bytes per LDS row

#define FOLD_ROWS 8
#define FOLD_BLOCKS (N_DIM / FOLD_ROWS)   // 512

typedef __attribute__((ext_vector_type(8))) short bf16x8;
typedef __attribute__((ext_vector_type(4))) float f32x4;

__device__ __forceinline__ ushort f2bf(float f) {
  union { float f; unsigned u; } v; v.f = f;
  unsigned u = v.u;
  u += 0x7FFF + ((u >> 16) & 1);   // round-to-nearest-even
  return (ushort)(u >> 16);
}

// ---- fused pre-pass (r8, measured at its ~288MB HBM floor) ----
__global__ __launch_bounds__(256) void prepass_kernel(
    const float* __restrict__ x, ushort* __restrict__ xb,
    const float* __restrict__ W, const float* __restrict__ A,
    const float* __restrict__ Bl, ushort* __restrict__ wb, long n4) {
  if (blockIdx.x < FOLD_BLOCKS) {
    const int o0 = blockIdx.x * FOLD_ROWS;
#pragma unroll 1
    for (int j = 0; j < 4; ++j) {
      const int d0 = (threadIdx.x + j * 256) * 4;
      float4 a[R_DIM];
#pragma unroll
      for (int r = 0; r < R_DIM; ++r)
        a[r] = *(const float4*)(A + (size_t)r * K_DIM + d0);
#pragma unroll 1
      for (int rr = 0; rr < FOLD_ROWS; ++rr) {
        const int o = o0 + rr;
        float4 w = *(const float4*)(W + (size_t)o * K_DIM + d0);
        float s0 = w.x, s1 = w.y, s2 = w.z, s3 = w.w;
#pragma unroll
        for (int r = 0; r < R_DIM; ++r) {
          const float bv = Bl[o * R_DIM + r] * SCALING_F;  // uniform -> sgpr
          s0 += bv * a[r].x; s1 += bv * a[r].y;
          s2 += bv * a[r].z; s3 += bv * a[r].w;
        }
        ushort4 ob;
        ob.x = f2bf(s0); ob.y = f2bf(s1); ob.z = f2bf(s2); ob.w = f2bf(s3);
        *(ushort4*)(wb + (size_t)o * K_DIM + d0) = ob;
      }
    }
  } else {
    long i = (long)(blockIdx.x - FOLD_BLOCKS) * blockDim.x + threadIdx.x;
    long stride = 2048L * blockDim.x;
    for (; i < n4; i += stride) {
      long idx = i * 4;
      float4 v = *(const float4*)(x + idx);
      ushort4 o;
      o.x = f2bf(v.x); o.y = f2bf(v.y); o.z = f2bf(v.z); o.w = f2bf(v.w);
      *(ushort4*)(xb + idx) = o;
    }
  }
}

// ============================ 256x256 8-phase GEMM ============================
// r6 (16x16x32 MFMA, 0-conflict swizzle, global_load_lds, identical register
// sets/stage schedule/vmcnt counts) with ONE barrier per phase instead of two.
// Body_p := [bar; lgkm(0); setprio(1); 16 MFMA; setprio(0); reads(p+1);
//            stages(S_p); (vmcnt at p=3,7)].
// Mechanism: without the close-barrier, each wave issues its next-phase
// ds_reads right after ITS OWN MFMA cluster — reads drain in the LDS pipe
// while slower waves still compute, so body-top lgkm(0) finds them retired
// (MFMA pipe and LDS pipe overlap instead of alternating).
// WAR safety: every body-top lgkm(0) retires all of the wave's prior reads,
// so a region staged >=2 bodies after its last read-issue (r6's schedule;
// A-even [0,8K)u[16K,24K), A-odd, B-halves are disjoint regions) has a
// barrier + reader-lgkm(0) between read and overwrite — verified all pairs.
// Publish: vmcnt(4) end-of-body-3 (buf1 tile t1; drains prologue/Ao, keeps
// B0,B1(t2)) and end-of-body-7 (buf0 tile t2; keeps B0,B1(t3)); vmcnt(0)
// at last-iter body-3. Identical counts to r6 (two passing rounds).

#define RS 8192L  // global row stride bytes (K_DIM * 2)

#define GLOAD(SRC, LOFF)                                                    \
  __builtin_amdgcn_global_load_lds(                                         \
      (const __attribute__((address_space(1))) void*)(SRC),                 \
      (__attribute__((address_space(3))) void*)(smem + (LOFF)), 16, 0, 0)

#define LDSA(BUF) ((BUF) * 32768)
#define LDSB(BUF) (65536 + (BUF) * 32768)

#define ST_A_EVEN(T, BUF) do {                                              \
    GLOAD(aS + (size_t)(T) * 128,            LDSA(BUF) + ldsDst);           \
    GLOAD(aS + (size_t)(T) * 128 + 128 * RS, LDSA(BUF) + 16384 + ldsDst); } while (0)
#define ST_A_ODD(T, BUF) do {                                               \
    GLOAD(aS + (size_t)(T) * 128 + 64 * RS,  LDSA(BUF) + 8192 + ldsDst);    \
    GLOAD(aS + (size_t)(T) * 128 + 192 * RS, LDSA(BUF) + 24576 + ldsDst); } while (0)
#define ST_B_H0(T, BUF) do {                                                \
    GLOAD(bS + (size_t)(T) * 128,            LDSB(BUF) + ldsDst);           \
    GLOAD(bS + (size_t)(T) * 128 + 64 * RS,  LDSB(BUF) + 8192 + ldsDst); } while (0)
#define ST_B_H1(T, BUF) do {                                                \
    GLOAD(bS + (size_t)(T) * 128 + 128 * RS, LDSB(BUF) + 16384 + ldsDst);   \
    GLOAD(bS + (size_t)(T) * 128 + 192 * RS, LDSB(BUF) + 24576 + ldsDst); } while (0)

#define LDA(M, CK, BUF) (*(const bf16x8*)(smem + LDSA(BUF) + aRd + (M) * 2048 + (CK)))
#define LDB(N, CK, BUF) (*(const bf16x8*)(smem + LDSB(BUF) + bRd + (N) * 2048 + (CK)))

#define PF_A(MB, CK, BUF) do {                                              \
    afr[0] = LDA((MB) + 0, CK, BUF); afr[1] = LDA((MB) + 1, CK, BUF);       \
    afr[2] = LDA((MB) + 2, CK, BUF); afr[3] = LDA((MB) + 3, CK, BUF); } while (0)
#define PF_B_ALL(BUF) do {                                                  \
    bfr[0][0] = LDB(0, cK0, BUF); bfr[0][1] = LDB(0, cK1, BUF);             \
    bfr[1][0] = LDB(1, cK0, BUF); bfr[1][1] = LDB(1, cK1, BUF);             \
    bfr[2][0] = LDB(2, cK0, BUF); bfr[2][1] = LDB(2, cK1, BUF);             \
    bfr[3][0] = LDB(3, cK0, BUF); bfr[3][1] = LDB(3, cK1, BUF); } while (0)

#define MFMA16(MB, KK) do {                                                 \
    _Pragma("unroll") for (int mm = 0; mm < 4; ++mm)                        \
      _Pragma("unroll") for (int nn = 0; nn < 4; ++nn)                      \
        acc[(MB) + mm][nn] = __builtin_amdgcn_mfma_f32_16x16x32_bf16(       \
            afr[mm], bfr[nn][KK], acc[(MB) + mm][nn], 0, 0, 0); } while (0)

// single-barrier body core: bar -> drain own reads -> prioritized MFMA
#define BODY(MB, KK) do {                                                   \
    __builtin_amdgcn_s_barrier();                                           \
    asm volatile("s_waitcnt lgkmcnt(0)");                                   \
    __builtin_amdgcn_s_setprio(1);                                          \
    MFMA16(MB, KK);                                                         \
    __builtin_amdgcn_s_setprio(0); } while (0)

__global__ __launch_bounds__(512, 2) void gemm_lora_kernel(
    const ushort* __restrict__ Ab, const ushort* __restrict__ Bb,
    const float* __restrict__ bias, float* __restrict__ C) {
  __shared__ char smem[131072];

  const int tid = threadIdx.x;
  const int wave = tid >> 6, lane = tid & 63;
  const int wm = wave >> 2, wn = wave & 3;
  const int fr = lane & 15, fq = lane >> 4;

  // XCD-aware mapping: XCD x owns bm in [4x,4x+4); bn sweeps. grid=512 (%8==0).
  const int bid = blockIdx.x;
  const int bm = ((bid & 7) << 2) + ((bid >> 3) & 3);
  const int bn = bid >> 5;

  // staging source (inverse-swizzled global addresses, 16B chunks)
  const int trow = tid >> 3;
  const int tswz = ((tid & 7) << 4) ^ ((trow & 7) << 4);
  const char* aS = (const char*)Ab + (size_t)(bm * BM + trow) * RS + tswz;
  const char* bS = (const char*)Bb + (size_t)(bn * BN + trow) * RS + tswz;
  const int ldsDst = tid << 4;

  // swizzled ds_read byte columns (verified 0-conflict r2/r5/r6/r11)
  const int sa  = (fr & 7) << 4;
  const int cK0 = (fq << 4) ^ sa;
  const int cK1 = (64 | (fq << 4)) ^ sa;
  const int aRd = ((wm << 7) + fr) << 7;   // (wm*128 + fr) * 128 B
  const int bRd = ((wn << 6) + fr) << 7;   // (wn*64  + fr) * 128 B

  f32x4 acc[8][4];
#pragma unroll
  for (int m = 0; m < 8; ++m)
#pragma unroll
    for (int n = 0; n < 4; ++n) acc[m][n] = (f32x4){0.f, 0.f, 0.f, 0.f};
  bf16x8 afr[4], bfr[4][2];

  // prologue: tile0 -> buf0 (full); tile1 -> buf1 (B0,B1,Ae). 14 loads.
  ST_B_H0(0, 0); ST_B_H1(0, 0); ST_A_EVEN(0, 0); ST_A_ODD(0, 0);
  ST_B_H0(1, 1); ST_B_H1(1, 1); ST_A_EVEN(1, 1);
  asm volatile("s_waitcnt vmcnt(6)" ::: "memory");  // tile0 fully landed
  __builtin_amdgcn_s_barrier();                      // ...and visible to all
  // reads for body 1 (retired at body 1's lgkm(0))
  PF_B_ALL(0);
  PF_A(0, cK0, 0);

  const int NIT = K_DIM / (2 * BK);  // 32
#pragma unroll 1
  for (int i = 0; i < NIT; ++i) {
    const int t1 = 2 * i + 1, t2 = 2 * i + 2, t3 = 2 * i + 3;
    const bool last = (i == NIT - 1);

    // ---- body 1: buf0 (m0-3,k0) | reads(2): A(m0-3,k1,b0) | stage Ao(t1,b1)
    BODY(0, 0);
    PF_A(0, cK1, 0);
    ST_A_ODD(t1, 1);

    // ---- body 2: buf0 (m0-3,k1) | reads(3): A(m4-7,k0,b0) | stage B0(t2,b0)
    BODY(0, 1);
    PF_A(4, cK0, 0);
    if (!last) ST_B_H0(t2, 0);

    // ---- body 3: buf0 (m4-7,k0) | reads(4): A(m4-7,k1,b0) | stage B1(t2,b0)
    //      vmcnt publish of buf1(t1) before bar_3
    BODY(4, 0);
    PF_A(4, cK1, 0);
    if (!last) ST_B_H1(t2, 0);
    if (last) asm volatile("s_waitcnt vmcnt(0)" ::: "memory");
    else      asm volatile("s_waitcnt vmcnt(4)" ::: "memory");

    // ---- body 4: buf0 (m4-7,k1) | reads(5): B-all(b1)+A(m0-3,k0,b1)
    //      (buf1 published at bar_4-entry) | stage Ae(t2,b0)
    BODY(4, 1);
    PF_B_ALL(1);
    PF_A(0, cK0, 1);
    if (!last) ST_A_EVEN(t2, 0);

    // ---- body 5: buf1 (m0-3,k0) | reads(6): A(m0-3,k1,b1) | stage Ao(t2,b0)
    BODY(0, 0);
    PF_A(0, cK1, 1);
    if (!last) ST_A_ODD(t2, 0);

    // ---- body 6: buf1 (m0-3,k1) | reads(7): A(m4-7,k0,b1) | stage B0(t3,b1)
    BODY(0, 1);
    PF_A(4, cK0, 1);
    if (!last) ST_B_H0(t3, 1);

    // ---- body 7: buf1 (m4-7,k0) | reads(8): A(m4-7,k1,b1) | stage B1(t3,b1)
    //      vmcnt publish of buf0(t2) before bar_7
    BODY(4, 0);
    PF_A(4, cK1, 1);
    if (!last) {
      ST_B_H1(t3, 1);
      asm volatile("s_waitcnt vmcnt(4)" ::: "memory");
    }

    // ---- body 8: buf1 (m4-7,k1) | reads(1'): B-all(b0)+A(m0-3,k0,b0)
    //      | stage Ae(t3,b1)
    BODY(4, 1);
    if (!last) {
      PF_B_ALL(0);
      PF_A(0, cK0, 0);
      ST_A_EVEN(t3, 1);
    }
  }

  // epilogue: C/D layout col=lane&15, row=(lane>>4)*4+reg  [m89/m91]
  const int ccol0 = bn * BN + wn * 64 + fr;
  float bv[4];
#pragma unroll
  for (int n = 0; n < 4; ++n) bv[n] = bias[ccol0 + n * 16];
  const int crow0 = bm * BM + wm * 128 + fq * 4;
#pragma unroll
  for (int m = 0; m < 8; ++m)
#pragma unroll
    for (int n = 0; n < 4; ++n)
#pragma unroll
      for (int v = 0; v < 4; ++v) {
        int row = crow0 + m * 16 + v;
        C[(size_t)row * N_DIM + ccol0 + n * 16] = acc[m][n][v] + bv[n];
      }
}

extern "C" void kernel_launch(void* const* d_in, const int* in_sizes, int n_in,
                              void* d_out, int out_size, void* d_ws, size_t ws_size,
                              hipStream_t stream) {
  const float* x  = (const float*)d_in[0];   // [M, K]
  const float* W  = (const float*)d_in[1];   // [N, K]
  const float* b  = (const float*)d_in[2];   // [N]
  const float* lA = (const float*)d_in[3];   // [R, K]
  const float* lB = (const float*)d_in[4];   // [N, R]
  float* out = (float*)d_out;                // [M, N]

  const int M = in_sizes[0] / K_DIM;  // 8192

  ushort* xb = (ushort*)d_ws;                 // 64 MB
  ushort* wb = xb + (size_t)M * K_DIM;        // 32 MB

  long n4 = (long)M * K_DIM / 4;
  prepass_kernel<<<FOLD_BLOCKS + 2048, 256, 0, stream>>>(x, xb, W, lA, lB, wb, n4);
  gemm_lora_kernel<<<(M / BM) * (N_DIM / BN), 512, 0, stream>>>(xb, wb, b, out);
}